// Round 17
// baseline (165.106 us; speedup 1.0000x reference)
//
#include <hip/hip_runtime.h>
#include <hip/hip_bf16.h>
#include <cstdint>

#define NPTS 4096
#define NB 8
#define KNN 20
#define CAP 40

// LDS union layout (bytes): [0,64K) pts  ->  reused as A[64][132] + h1[64][68]
#define CVAL_OFF 65536
#define CIDX_OFF (CVAL_OFF + 8 * 4 * CAP * 4)
#define SEL_OFF  (CIDX_OFF + 8 * 4 * CAP * 4)
#define SMEM_SZ  (SEL_OFF + 8 * 4 * KNN * 4)     // 78336 B
#define H1_OFF   33792                            // 64*132*4

__device__ __forceinline__ float lrelu(float x) { return x >= 0.0f ? x : 0.2f * x; }

__device__ __forceinline__ uint32_t enc_f32(float f) {
    uint32_t u = __float_as_uint(f);
    return (u & 0x80000000u) ? ~u : (u | 0x80000000u);
}
__device__ __forceinline__ float dec_f32(uint32_t u) {
    return (u & 0x80000000u) ? __uint_as_float(u ^ 0x80000000u) : __uint_as_float(~u);
}

// XOR bank swizzle (verified R8: conflicts 110K -> 0 in both access patterns)
__device__ __forceinline__ int physidx(int i) {
    return (i & ~63) | ((i ^ (i >> 6)) & 63);
}

// ---------------------------------------------------------------------------
// K1: fused kNN + EdgeConv + max-k + pconv chain + max-pts (R16 structure).
//     R17 change: P1 carries l0's INDEX; P3a emits single-element lanes
//     (l0 >= theta > l1) directly via one ballot-compact step -- only lanes
//     with l1 >= theta (~3/row) need the full column rescan.
//     Soundness: u >= th, u != l0  =>  u <= l1  =>  lane has l1 >= th.
// ---------------------------------------------------------------------------
__global__ __launch_bounds__(512, 4) void k1_fused(
        const float* __restrict__ x,
        const float* __restrict__ W0, const float* __restrict__ b0,
        const float* __restrict__ s0, const float* __restrict__ t0,
        const float* __restrict__ W1, const float* __restrict__ b1,
        const float* __restrict__ s1, const float* __restrict__ t1,
        const float* __restrict__ W2, const float* __restrict__ b2,
        const float* __restrict__ s2, const float* __restrict__ t2,
        const float* __restrict__ W3, const float* __restrict__ b3,
        const float* __restrict__ s3, const float* __restrict__ t3,
        uint32_t* __restrict__ gmax)
{
    __shared__ alignas(16) char smem[SMEM_SZ];
    __shared__ float sW0[64 * 6];
    __shared__ float sB[64], sS[64], sT[64];
    __shared__ uint32_t bmax[128];

    float4* pts = (float4*)smem;

    const int blk = blockIdx.x;
    const int b = blk >> 6;               // 64 blocks per batch
    const int rowbase = (blk & 63) << 6;  // 64 rows per block
    const int t = threadIdx.x;
    const int lane = t & 63;
    const int w = t >> 6;                 // wave 0..7

    const float* xb = x + (size_t)b * (NPTS * 3);

    // ---- single staging of all 4096 points ----
    for (int i = t; i < NPTS; i += 512) {
        float x0 = xb[3 * i], x1 = xb[3 * i + 1], x2 = xb[3 * i + 2];
        float pp = __fadd_rn(__fadd_rn(__fmul_rn(x0, x0), __fmul_rn(x1, x1)),
                             __fmul_rn(x2, x2));
        pts[physidx(i)] = make_float4(x0 + x0, x1 + x1, x2 + x2, -pp);
    }
    if (t < 64) {
        #pragma unroll
        for (int c = 0; c < 6; c++) sW0[t * 6 + c] = W0[t * 6 + c];
        sB[t] = b0[t]; sS[t] = s0[t]; sT[t] = t0[t];
    }
    if (t < 128) bmax[t] = 0u;

    const int r0 = rowbase + w * 8;
    float qx[8], qy[8], qz[8];
    #pragma unroll
    for (int rr = 0; rr < 8; rr++) {
        qx[rr] = xb[3 * (r0 + rr) + 0];
        qy[rr] = xb[3 * (r0 + rr) + 1];
        qz[rr] = xb[3 * (r0 + rr) + 2];
    }
    __syncthreads();

    // ---- P1: per-lane top-2 values + top-1 index, 8 rows ----
    float l0[8], l1v[8];
    int   l0i[8];
    #pragma unroll
    for (int rr = 0; rr < 8; rr++) {
        l0[rr] = -INFINITY; l1v[rr] = -INFINITY; l0i[rr] = 0x7FFFFFFF;
    }

    #pragma unroll 4
    for (int j = 0; j < 64; j++) {
        const float4 p = pts[(j << 6) | ((lane ^ j) & 63)];
        const int m = (j << 6) | lane;
        #pragma unroll
        for (int rr = 0; rr < 8; rr++) {
            float u = fmaf(qx[rr], p.x, fmaf(qy[rr], p.y, fmaf(qz[rr], p.z, p.w)));
            bool g0 = u > l0[rr];                                 // strict: first idx on ties
            l1v[rr] = __builtin_amdgcn_fmed3f(u, l0[rr], l1v[rr]);
            l0[rr] = fmaxf(u, l0[rr]);
            l0i[rr] = g0 ? m : l0i[rr];
        }
    }

    const float wa0 = sW0[lane * 6 + 0], wa1 = sW0[lane * 6 + 1], wa2 = sW0[lane * 6 + 2];
    const float wa0h = 0.5f * wa0, wa1h = 0.5f * wa1, wa2h = 0.5f * wa2;  // pts hold 2p
    const float wd0 = sW0[lane * 6 + 3] - wa0;
    const float wd1 = sW0[lane * 6 + 4] - wa1;
    const float wd2 = sW0[lane * 6 + 5] - wa2;

    float* cvalb = (float*)(smem + CVAL_OFF);
    int*   cidxb = (int*)(smem + CIDX_OFF);
    int*   selb  = (int*)(smem + SEL_OFF);

    float hz[8];   // h0 output, carried in registers across the LDS reuse

    for (int half = 0; half < 2; half++) {
        const int R = half * 4;

        // P2: 16-bit radix-ballot theta~
        uint32_t e0[4], e1[4], pr[4];
        #pragma unroll
        for (int rr = 0; rr < 4; rr++) {
            e0[rr] = enc_f32(l0[R + rr]);
            e1[rr] = enc_f32(l1v[R + rr]);
            pr[rr] = 0u;
        }
        for (int bit = 31; bit >= 16; bit--) {
            #pragma unroll
            for (int rr = 0; rr < 4; rr++) {
                uint32_t T = pr[rr] | (1u << bit);
                int c = __popcll(__ballot(e0[rr] >= T)) + __popcll(__ballot(e1[rr] >= T));
                if (c >= KNN) pr[rr] = T;
            }
        }
        float th[4];
        #pragma unroll
        for (int rr = 0; rr < 4; rr++) th[rr] = dec_f32(pr[rr]);

        // P3a: collect all u >= theta~.
        //   single-element lanes (l0>=th>l1): direct ballot-compacted emit
        //   multi-element lanes (l1>=th):     full column rescan (rare, ~3/row)
        int nsel[4];
        #pragma unroll
        for (int rr = 0; rr < 4; rr++) {
            float* cval = cvalb + (w * 4 + rr) * CAP;
            int*   cidx = cidxb + (w * 4 + rr) * CAP;
            const float thv = th[rr];
            unsigned long long M1 = __ballot(l1v[R + rr] >= thv);
            bool single = (l0[R + rr] >= thv) && (l1v[R + rr] < thv);
            unsigned long long m0 = __ballot(single);
            if (single) {
                int pos = __popcll(m0 & ((1ull << lane) - 1ull));
                cval[pos] = l0[R + rr];
                cidx[pos] = l0i[R + rr];
            }
            int base = __popcll(m0);
            unsigned long long lm = M1;
            while (lm) {
                int L = __ffsll(lm) - 1; lm &= lm - 1;
                const float4 p = pts[(lane << 6) | ((L ^ lane) & 63)];
                float u = fmaf(qx[R + rr], p.x,
                          fmaf(qy[R + rr], p.y, fmaf(qz[R + rr], p.z, p.w)));
                unsigned long long hit = __ballot(u >= thv);
                if (u >= thv) {
                    int pos = base + __popcll(hit & ((1ull << lane) - 1ull));
                    if (pos < CAP) { cval[pos] = u; cidx[pos] = (lane << 6) | L; }
                }
                base += __popcll(hit);
            }
            nsel[rr] = min(base, CAP);
        }

        // P3b: exact top-20 by (value desc, idx asc) when n > 20
        #pragma unroll
        for (int rr = 0; rr < 4; rr++) {
            int n = nsel[rr];
            if (n > KNN) {
                float* cval = cvalb + (w * 4 + rr) * CAP;
                int*   cidx = cidxb + (w * 4 + rr) * CAP;
                int*   sel  = selb  + (w * 4 + rr) * KNN;
                bool act = lane < n;
                float ve = act ? cval[lane] : -INFINITY;
                int   ie = act ? cidx[lane] : 0x7FFFFFFF;
                int rk = 0;
                for (int f = 0; f < n; f++) {
                    float vf = cval[f];
                    int   if_ = cidx[f];
                    rk += ((vf > ve) || (vf == ve && if_ < ie)) ? 1 : 0;
                }
                if (act && rk < KNN) sel[rk] = ie;
            }
        }

        // P3c: consume -> hz (no global write)
        #pragma unroll
        for (int rr = 0; rr < 4; rr++) {
            int n = nsel[rr];
            bool ranked = n > KNN;
            int cnt20 = ranked ? KNN : n;
            const int* cidx = cidxb + (w * 4 + rr) * CAP;
            const int* sel  = selb  + (w * 4 + rr) * KNN;
            float mm = -INFINITY;
            for (int e = 0; e < cnt20; e++) {
                int g = ranked ? sel[e] : cidx[e];
                float4 p = pts[physidx(g)];
                float dotp = fmaf(wa2h, p.z, fmaf(wa1h, p.y, wa0h * p.x));
                mm = fmaxf(mm, dotp);
            }
            float cterm = fmaf(wd2, qz[R + rr], fmaf(wd1, qy[R + rr], wd0 * qx[R + rr]));
            float z = (mm + cterm + sB[lane]) * sS[lane] + sT[lane];
            hz[R + rr] = lrelu(z);
        }
    }

    // ================= MLP phase: reuse LDS =================
    __syncthreads();     // pts + collect arrays now dead
    float* A  = (float*)smem;            // [64][132]: h0 (64c) then h2 (128c)
    float* h1 = (float*)(smem + H1_OFF); // [64][68]

    {
        const int row = w * 8;
        #pragma unroll
        for (int rr = 0; rr < 8; rr++) A[(row + rr) * 132 + lane] = hz[rr];
    }
    __syncthreads();

    const int ps = t & 15;   // 16 point-slots, 4 pts each: {ps, ps+16, ps+32, ps+48}
    const int og = t >> 4;   // 0..31

    // ---- L1: 64 -> 64 ; outs o = og*2+[0,2) ----
    {
        float acc[4][2] = {};
        #pragma unroll
        for (int c = 0; c < 64; c += 4) {
            float4 h[4];
            #pragma unroll
            for (int pp = 0; pp < 4; pp++)
                h[pp] = *(const float4*)&A[(ps + 16 * pp) * 132 + c];
            #pragma unroll
            for (int r = 0; r < 2; r++) {
                float4 wv = *(const float4*)&W1[(og * 2 + r) * 64 + c];
                #pragma unroll
                for (int pp = 0; pp < 4; pp++)
                    acc[pp][r] += h[pp].x * wv.x + h[pp].y * wv.y
                                + h[pp].z * wv.z + h[pp].w * wv.w;
            }
        }
        #pragma unroll
        for (int r = 0; r < 2; r++) {
            int o = og * 2 + r;
            float bb = b1[o], ss = s1[o], tt = t1[o];
            #pragma unroll
            for (int pp = 0; pp < 4; pp++)
                h1[(ps + 16 * pp) * 68 + o] = lrelu((acc[pp][r] + bb) * ss + tt);
        }
    }
    __syncthreads();

    // ---- L2: 64 -> 128 ; outs o = og*4+[0,4) ; h2 overwrites A ----
    {
        float acc[4][4] = {};
        #pragma unroll
        for (int c = 0; c < 64; c += 4) {
            float4 h[4];
            #pragma unroll
            for (int pp = 0; pp < 4; pp++)
                h[pp] = *(const float4*)&h1[(ps + 16 * pp) * 68 + c];
            #pragma unroll
            for (int r = 0; r < 4; r++) {
                float4 wv = *(const float4*)&W2[(og * 4 + r) * 64 + c];
                #pragma unroll
                for (int pp = 0; pp < 4; pp++)
                    acc[pp][r] += h[pp].x * wv.x + h[pp].y * wv.y
                                + h[pp].z * wv.z + h[pp].w * wv.w;
            }
        }
        __syncthreads();   // all L1-era reads of A done before overwrite
        #pragma unroll
        for (int pp = 0; pp < 4; pp++) {
            float4 o4; float* po = (float*)&o4;
            #pragma unroll
            for (int r = 0; r < 4; r++) {
                int o = og * 4 + r;
                po[r] = lrelu((acc[pp][r] + b2[o]) * s2[o] + t2[o]);
            }
            *(float4*)&A[(ps + 16 * pp) * 132 + og * 4] = o4;
        }
    }
    __syncthreads();

    // ---- L3: 128 -> 128 + max over the block's 64 points ----
    {
        float acc[4][4] = {};
        #pragma unroll
        for (int c = 0; c < 128; c += 4) {
            float4 h[4];
            #pragma unroll
            for (int pp = 0; pp < 4; pp++)
                h[pp] = *(const float4*)&A[(ps + 16 * pp) * 132 + c];
            #pragma unroll
            for (int r = 0; r < 4; r++) {
                float4 wv = *(const float4*)&W3[(og * 4 + r) * 128 + c];
                #pragma unroll
                for (int pp = 0; pp < 4; pp++)
                    acc[pp][r] += h[pp].x * wv.x + h[pp].y * wv.y
                                + h[pp].z * wv.z + h[pp].w * wv.w;
            }
        }
        float m[4];
        #pragma unroll
        for (int r = 0; r < 4; r++)
            m[r] = fmaxf(fmaxf(acc[0][r], acc[1][r]), fmaxf(acc[2][r], acc[3][r]));
        #pragma unroll
        for (int off = 1; off < 16; off <<= 1) {
            #pragma unroll
            for (int r = 0; r < 4; r++)
                m[r] = fmaxf(m[r], __shfl_xor(m[r], off));
        }
        if (ps == 0) {
            #pragma unroll
            for (int r = 0; r < 4; r++) {
                int o = og * 4 + r;
                float z = lrelu((m[r] + b3[o]) * s3[o] + t3[o]);
                atomicMax(&bmax[o], enc_f32(z));
            }
        }
    }
    __syncthreads();
    if (t < 128) atomicMax(&gmax[b * 128 + t], bmax[t]);
}

// ---------------------------------------------------------------------------
// K3: head 128 -> 512 (affine+lrelu) -> 1024.  64 blocks (8 batch x 8 chunk).
// ---------------------------------------------------------------------------
__global__ __launch_bounds__(256) void k3_head(
        const uint32_t* __restrict__ gmax,
        const float* __restrict__ W4, const float* __restrict__ b4,
        const float* __restrict__ s4, const float* __restrict__ t4,
        const float* __restrict__ W5, const float* __restrict__ b5,
        float* __restrict__ out)
{
    __shared__ float sIn[128];
    __shared__ float sH4[512];
    const int t = threadIdx.x;
    const int b = blockIdx.x >> 3;
    const int chunk = blockIdx.x & 7;

    if (t < 128) sIn[t] = dec_f32(gmax[b * 128 + t]);
    __syncthreads();

    #pragma unroll
    for (int rep = 0; rep < 2; rep++) {
        int o = t + rep * 256;
        const float4* wr = (const float4*)&W4[(size_t)o * 128];
        float acc = 0.f;
        for (int c4 = 0; c4 < 32; c4++) {
            float4 wv = wr[c4];
            acc += sIn[c4 * 4] * wv.x + sIn[c4 * 4 + 1] * wv.y
                 + sIn[c4 * 4 + 2] * wv.z + sIn[c4 * 4 + 3] * wv.w;
        }
        float z = (acc + b4[o]) * s4[o] + t4[o];
        sH4[o] = lrelu(z);
    }
    __syncthreads();

    if (t < 128) {
        int o = chunk * 128 + t;
        const float4* wr = (const float4*)&W5[(size_t)o * 512];
        float acc = 0.f;
        for (int c4 = 0; c4 < 128; c4++) {
            float4 wv = wr[c4];
            acc += sH4[c4 * 4] * wv.x + sH4[c4 * 4 + 1] * wv.y
                 + sH4[c4 * 4 + 2] * wv.z + sH4[c4 * 4 + 3] * wv.w;
        }
        out[(size_t)b * 1024 + o] = acc + b5[o];
    }
}

// ---------------------------------------------------------------------------
extern "C" void kernel_launch(void* const* d_in, const int* in_sizes, int n_in,
                              void* d_out, int out_size, void* d_ws, size_t ws_size,
                              hipStream_t stream) {
    (void)in_sizes; (void)n_in; (void)out_size; (void)ws_size;
    const float* x  = (const float*)d_in[0];
    const float* W0 = (const float*)d_in[1];
    const float* b0 = (const float*)d_in[2];
    const float* s0 = (const float*)d_in[3];
    const float* t0 = (const float*)d_in[4];
    const float* W1 = (const float*)d_in[5];
    const float* b1 = (const float*)d_in[6];
    const float* s1 = (const float*)d_in[7];
    const float* t1 = (const float*)d_in[8];
    const float* W2 = (const float*)d_in[9];
    const float* b2 = (const float*)d_in[10];
    const float* s2 = (const float*)d_in[11];
    const float* t2 = (const float*)d_in[12];
    const float* W3 = (const float*)d_in[13];
    const float* b3 = (const float*)d_in[14];
    const float* s3 = (const float*)d_in[15];
    const float* t3 = (const float*)d_in[16];
    const float* W4 = (const float*)d_in[17];
    const float* b4 = (const float*)d_in[18];
    const float* s4 = (const float*)d_in[19];
    const float* t4 = (const float*)d_in[20];
    const float* W5 = (const float*)d_in[21];
    const float* b5 = (const float*)d_in[22];

    uint32_t* gmax = (uint32_t*)d_ws;     // [8][128] u32

    hipMemsetAsync(gmax, 0, NB * 128 * sizeof(uint32_t), stream);  // enc(-inf) floor

    k1_fused<<<dim3(512), dim3(512), 0, stream>>>(
        x, W0, b0, s0, t0,
        W1, b1, s1, t1,
        W2, b2, s2, t2,
        W3, b3, s3, t3, gmax);
    k3_head<<<dim3(64), dim3(256), 0, stream>>>(gmax, W4, b4, s4, t4, W5, b5,
                                                (float*)d_out);
}

// Round 18
// 125.817 us; speedup vs baseline: 1.3123x; 1.3123x over previous
//
#include <hip/hip_runtime.h>
#include <hip/hip_bf16.h>
#include <cstdint>

#define NPTS 4096
#define NB 8
#define KNN 20
#define CAP 40

// LDS union layout (bytes): [0,64K) pts  ->  reused as A[64][132] + h1[64][68]
#define CVAL_OFF 65536
#define CIDX_OFF (CVAL_OFF + 8 * 4 * CAP * 4)
#define SEL_OFF  (CIDX_OFF + 8 * 4 * CAP * 4)
#define SMEM_SZ  (SEL_OFF + 8 * 4 * KNN * 4)     // 78336 B
#define H1_OFF   33792                            // 64*132*4

__device__ __forceinline__ float lrelu(float x) { return x >= 0.0f ? x : 0.2f * x; }

__device__ __forceinline__ uint32_t enc_f32(float f) {
    uint32_t u = __float_as_uint(f);
    return (u & 0x80000000u) ? ~u : (u | 0x80000000u);
}
__device__ __forceinline__ float dec_f32(uint32_t u) {
    return (u & 0x80000000u) ? __uint_as_float(u ^ 0x80000000u) : __uint_as_float(~u);
}

// XOR bank swizzle (verified R8: conflicts 110K -> 0 in both access patterns)
__device__ __forceinline__ int physidx(int i) {
    return (i & ~63) | ((i ^ (i >> 6)) & 63);
}

// ---------------------------------------------------------------------------
// K1: fused kNN + EdgeConv + max-k + pconv chain + max-pts (R16 structure,
//     MLP loops NOT unrolled -- R17's unroll pragmas caused 260MB scratch
//     spill).  R18 keeps only the P3a single-emit optimization:
//     lanes with l0 >= theta > l1 emit (l0, l0i) directly via ballot-compact;
//     only lanes with l1 >= theta (~3/row) need the full column rescan.
//     Soundness: u >= th and u != l0  =>  u <= l1  =>  that lane has l1 >= th.
// ---------------------------------------------------------------------------
__global__ __launch_bounds__(512, 4) void k1_fused(
        const float* __restrict__ x,
        const float* __restrict__ W0, const float* __restrict__ b0,
        const float* __restrict__ s0, const float* __restrict__ t0,
        const float* __restrict__ W1, const float* __restrict__ b1,
        const float* __restrict__ s1, const float* __restrict__ t1,
        const float* __restrict__ W2, const float* __restrict__ b2,
        const float* __restrict__ s2, const float* __restrict__ t2,
        const float* __restrict__ W3, const float* __restrict__ b3,
        const float* __restrict__ s3, const float* __restrict__ t3,
        uint32_t* __restrict__ gmax)
{
    __shared__ alignas(16) char smem[SMEM_SZ];
    __shared__ float sW0[64 * 6];
    __shared__ float sB[64], sS[64], sT[64];
    __shared__ uint32_t bmax[128];

    float4* pts = (float4*)smem;

    const int blk = blockIdx.x;
    const int b = blk >> 6;               // 64 blocks per batch
    const int rowbase = (blk & 63) << 6;  // 64 rows per block
    const int t = threadIdx.x;
    const int lane = t & 63;
    const int w = t >> 6;                 // wave 0..7

    const float* xb = x + (size_t)b * (NPTS * 3);

    // ---- single staging of all 4096 points ----
    for (int i = t; i < NPTS; i += 512) {
        float x0 = xb[3 * i], x1 = xb[3 * i + 1], x2 = xb[3 * i + 2];
        float pp = __fadd_rn(__fadd_rn(__fmul_rn(x0, x0), __fmul_rn(x1, x1)),
                             __fmul_rn(x2, x2));
        pts[physidx(i)] = make_float4(x0 + x0, x1 + x1, x2 + x2, -pp);
    }
    if (t < 64) {
        #pragma unroll
        for (int c = 0; c < 6; c++) sW0[t * 6 + c] = W0[t * 6 + c];
        sB[t] = b0[t]; sS[t] = s0[t]; sT[t] = t0[t];
    }
    if (t < 128) bmax[t] = 0u;

    const int r0 = rowbase + w * 8;
    float qx[8], qy[8], qz[8];
    #pragma unroll
    for (int rr = 0; rr < 8; rr++) {
        qx[rr] = xb[3 * (r0 + rr) + 0];
        qy[rr] = xb[3 * (r0 + rr) + 1];
        qz[rr] = xb[3 * (r0 + rr) + 2];
    }
    __syncthreads();

    // ---- P1: per-lane top-2 values + top-1 index, 8 rows ----
    float l0[8], l1v[8];
    int   l0i[8];
    #pragma unroll
    for (int rr = 0; rr < 8; rr++) {
        l0[rr] = -INFINITY; l1v[rr] = -INFINITY; l0i[rr] = 0x7FFFFFFF;
    }

    #pragma unroll 4
    for (int j = 0; j < 64; j++) {
        const float4 p = pts[(j << 6) | ((lane ^ j) & 63)];
        const int m = (j << 6) | lane;
        #pragma unroll
        for (int rr = 0; rr < 8; rr++) {
            float u = fmaf(qx[rr], p.x, fmaf(qy[rr], p.y, fmaf(qz[rr], p.z, p.w)));
            bool g0 = u > l0[rr];                                 // strict: first idx on ties
            l1v[rr] = __builtin_amdgcn_fmed3f(u, l0[rr], l1v[rr]);
            l0[rr] = fmaxf(u, l0[rr]);
            l0i[rr] = g0 ? m : l0i[rr];
        }
    }

    const float wa0 = sW0[lane * 6 + 0], wa1 = sW0[lane * 6 + 1], wa2 = sW0[lane * 6 + 2];
    const float wa0h = 0.5f * wa0, wa1h = 0.5f * wa1, wa2h = 0.5f * wa2;  // pts hold 2p
    const float wd0 = sW0[lane * 6 + 3] - wa0;
    const float wd1 = sW0[lane * 6 + 4] - wa1;
    const float wd2 = sW0[lane * 6 + 5] - wa2;

    float* cvalb = (float*)(smem + CVAL_OFF);
    int*   cidxb = (int*)(smem + CIDX_OFF);
    int*   selb  = (int*)(smem + SEL_OFF);

    float hz[8];   // h0 output, carried in registers across the LDS reuse

    for (int half = 0; half < 2; half++) {
        const int R = half * 4;

        // P2: 16-bit radix-ballot theta~
        uint32_t e0[4], e1[4], pr[4];
        #pragma unroll
        for (int rr = 0; rr < 4; rr++) {
            e0[rr] = enc_f32(l0[R + rr]);
            e1[rr] = enc_f32(l1v[R + rr]);
            pr[rr] = 0u;
        }
        for (int bit = 31; bit >= 16; bit--) {
            #pragma unroll
            for (int rr = 0; rr < 4; rr++) {
                uint32_t T = pr[rr] | (1u << bit);
                int c = __popcll(__ballot(e0[rr] >= T)) + __popcll(__ballot(e1[rr] >= T));
                if (c >= KNN) pr[rr] = T;
            }
        }
        float th[4];
        #pragma unroll
        for (int rr = 0; rr < 4; rr++) th[rr] = dec_f32(pr[rr]);

        // P3a: collect all u >= theta~.
        int nsel[4];
        #pragma unroll
        for (int rr = 0; rr < 4; rr++) {
            float* cval = cvalb + (w * 4 + rr) * CAP;
            int*   cidx = cidxb + (w * 4 + rr) * CAP;
            const float thv = th[rr];
            unsigned long long M1 = __ballot(l1v[R + rr] >= thv);
            bool single = (l0[R + rr] >= thv) && (l1v[R + rr] < thv);
            unsigned long long m0 = __ballot(single);
            if (single) {
                int pos = __popcll(m0 & ((1ull << lane) - 1ull));
                cval[pos] = l0[R + rr];
                cidx[pos] = l0i[R + rr];
            }
            int base = __popcll(m0);
            unsigned long long lm = M1;
            while (lm) {
                int L = __ffsll(lm) - 1; lm &= lm - 1;
                const float4 p = pts[(lane << 6) | ((L ^ lane) & 63)];
                float u = fmaf(qx[R + rr], p.x,
                          fmaf(qy[R + rr], p.y, fmaf(qz[R + rr], p.z, p.w)));
                unsigned long long hit = __ballot(u >= thv);
                if (u >= thv) {
                    int pos = base + __popcll(hit & ((1ull << lane) - 1ull));
                    if (pos < CAP) { cval[pos] = u; cidx[pos] = (lane << 6) | L; }
                }
                base += __popcll(hit);
            }
            nsel[rr] = min(base, CAP);
        }

        // P3b: exact top-20 by (value desc, idx asc) when n > 20
        #pragma unroll
        for (int rr = 0; rr < 4; rr++) {
            int n = nsel[rr];
            if (n > KNN) {
                float* cval = cvalb + (w * 4 + rr) * CAP;
                int*   cidx = cidxb + (w * 4 + rr) * CAP;
                int*   sel  = selb  + (w * 4 + rr) * KNN;
                bool act = lane < n;
                float ve = act ? cval[lane] : -INFINITY;
                int   ie = act ? cidx[lane] : 0x7FFFFFFF;
                int rk = 0;
                for (int f = 0; f < n; f++) {
                    float vf = cval[f];
                    int   if_ = cidx[f];
                    rk += ((vf > ve) || (vf == ve && if_ < ie)) ? 1 : 0;
                }
                if (act && rk < KNN) sel[rk] = ie;
            }
        }

        // P3c: consume -> hz (no global write)
        #pragma unroll
        for (int rr = 0; rr < 4; rr++) {
            int n = nsel[rr];
            bool ranked = n > KNN;
            int cnt20 = ranked ? KNN : n;
            const int* cidx = cidxb + (w * 4 + rr) * CAP;
            const int* sel  = selb  + (w * 4 + rr) * KNN;
            float mm = -INFINITY;
            for (int e = 0; e < cnt20; e++) {
                int g = ranked ? sel[e] : cidx[e];
                float4 p = pts[physidx(g)];
                float dotp = fmaf(wa2h, p.z, fmaf(wa1h, p.y, wa0h * p.x));
                mm = fmaxf(mm, dotp);
            }
            float cterm = fmaf(wd2, qz[R + rr], fmaf(wd1, qy[R + rr], wd0 * qx[R + rr]));
            float z = (mm + cterm + sB[lane]) * sS[lane] + sT[lane];
            hz[R + rr] = lrelu(z);
        }
    }

    // ================= MLP phase: reuse LDS =================
    __syncthreads();     // pts + collect arrays now dead
    float* A  = (float*)smem;            // [64][132]: h0 (64c) then h2 (128c)
    float* h1 = (float*)(smem + H1_OFF); // [64][68]

    {
        const int row = w * 8;
        #pragma unroll
        for (int rr = 0; rr < 8; rr++) A[(row + rr) * 132 + lane] = hz[rr];
    }
    __syncthreads();

    const int ps = t & 15;   // 16 point-slots, 4 pts each: {ps, ps+16, ps+32, ps+48}
    const int og = t >> 4;   // 0..31

    // ---- L1: 64 -> 64 ; outs o = og*2+[0,2) ----
    {
        float acc[4][2] = {};
        for (int c = 0; c < 64; c += 4) {
            float4 h[4];
            #pragma unroll
            for (int pp = 0; pp < 4; pp++)
                h[pp] = *(const float4*)&A[(ps + 16 * pp) * 132 + c];
            #pragma unroll
            for (int r = 0; r < 2; r++) {
                float4 wv = *(const float4*)&W1[(og * 2 + r) * 64 + c];
                #pragma unroll
                for (int pp = 0; pp < 4; pp++)
                    acc[pp][r] += h[pp].x * wv.x + h[pp].y * wv.y
                                + h[pp].z * wv.z + h[pp].w * wv.w;
            }
        }
        #pragma unroll
        for (int r = 0; r < 2; r++) {
            int o = og * 2 + r;
            float bb = b1[o], ss = s1[o], tt = t1[o];
            #pragma unroll
            for (int pp = 0; pp < 4; pp++)
                h1[(ps + 16 * pp) * 68 + o] = lrelu((acc[pp][r] + bb) * ss + tt);
        }
    }
    __syncthreads();

    // ---- L2: 64 -> 128 ; outs o = og*4+[0,4) ; h2 overwrites A ----
    {
        float acc[4][4] = {};
        for (int c = 0; c < 64; c += 4) {
            float4 h[4];
            #pragma unroll
            for (int pp = 0; pp < 4; pp++)
                h[pp] = *(const float4*)&h1[(ps + 16 * pp) * 68 + c];
            #pragma unroll
            for (int r = 0; r < 4; r++) {
                float4 wv = *(const float4*)&W2[(og * 4 + r) * 64 + c];
                #pragma unroll
                for (int pp = 0; pp < 4; pp++)
                    acc[pp][r] += h[pp].x * wv.x + h[pp].y * wv.y
                                + h[pp].z * wv.z + h[pp].w * wv.w;
            }
        }
        __syncthreads();   // all L1-era reads of A done before overwrite
        #pragma unroll
        for (int pp = 0; pp < 4; pp++) {
            float4 o4; float* po = (float*)&o4;
            #pragma unroll
            for (int r = 0; r < 4; r++) {
                int o = og * 4 + r;
                po[r] = lrelu((acc[pp][r] + b2[o]) * s2[o] + t2[o]);
            }
            *(float4*)&A[(ps + 16 * pp) * 132 + og * 4] = o4;
        }
    }
    __syncthreads();

    // ---- L3: 128 -> 128 + max over the block's 64 points ----
    {
        float acc[4][4] = {};
        for (int c = 0; c < 128; c += 4) {
            float4 h[4];
            #pragma unroll
            for (int pp = 0; pp < 4; pp++)
                h[pp] = *(const float4*)&A[(ps + 16 * pp) * 132 + c];
            #pragma unroll
            for (int r = 0; r < 4; r++) {
                float4 wv = *(const float4*)&W3[(og * 4 + r) * 128 + c];
                #pragma unroll
                for (int pp = 0; pp < 4; pp++)
                    acc[pp][r] += h[pp].x * wv.x + h[pp].y * wv.y
                                + h[pp].z * wv.z + h[pp].w * wv.w;
            }
        }
        float m[4];
        #pragma unroll
        for (int r = 0; r < 4; r++)
            m[r] = fmaxf(fmaxf(acc[0][r], acc[1][r]), fmaxf(acc[2][r], acc[3][r]));
        #pragma unroll
        for (int off = 1; off < 16; off <<= 1) {
            #pragma unroll
            for (int r = 0; r < 4; r++)
                m[r] = fmaxf(m[r], __shfl_xor(m[r], off));
        }
        if (ps == 0) {
            #pragma unroll
            for (int r = 0; r < 4; r++) {
                int o = og * 4 + r;
                float z = lrelu((m[r] + b3[o]) * s3[o] + t3[o]);
                atomicMax(&bmax[o], enc_f32(z));
            }
        }
    }
    __syncthreads();
    if (t < 128) atomicMax(&gmax[b * 128 + t], bmax[t]);
}

// ---------------------------------------------------------------------------
// K3: head 128 -> 512 (affine+lrelu) -> 1024.  64 blocks (8 batch x 8 chunk).
// ---------------------------------------------------------------------------
__global__ __launch_bounds__(256) void k3_head(
        const uint32_t* __restrict__ gmax,
        const float* __restrict__ W4, const float* __restrict__ b4,
        const float* __restrict__ s4, const float* __restrict__ t4,
        const float* __restrict__ W5, const float* __restrict__ b5,
        float* __restrict__ out)
{
    __shared__ float sIn[128];
    __shared__ float sH4[512];
    const int t = threadIdx.x;
    const int b = blockIdx.x >> 3;
    const int chunk = blockIdx.x & 7;

    if (t < 128) sIn[t] = dec_f32(gmax[b * 128 + t]);
    __syncthreads();

    #pragma unroll
    for (int rep = 0; rep < 2; rep++) {
        int o = t + rep * 256;
        const float4* wr = (const float4*)&W4[(size_t)o * 128];
        float acc = 0.f;
        for (int c4 = 0; c4 < 32; c4++) {
            float4 wv = wr[c4];
            acc += sIn[c4 * 4] * wv.x + sIn[c4 * 4 + 1] * wv.y
                 + sIn[c4 * 4 + 2] * wv.z + sIn[c4 * 4 + 3] * wv.w;
        }
        float z = (acc + b4[o]) * s4[o] + t4[o];
        sH4[o] = lrelu(z);
    }
    __syncthreads();

    if (t < 128) {
        int o = chunk * 128 + t;
        const float4* wr = (const float4*)&W5[(size_t)o * 512];
        float acc = 0.f;
        for (int c4 = 0; c4 < 128; c4++) {
            float4 wv = wr[c4];
            acc += sH4[c4 * 4] * wv.x + sH4[c4 * 4 + 1] * wv.y
                 + sH4[c4 * 4 + 2] * wv.z + sH4[c4 * 4 + 3] * wv.w;
        }
        out[(size_t)b * 1024 + o] = acc + b5[o];
    }
}

// ---------------------------------------------------------------------------
extern "C" void kernel_launch(void* const* d_in, const int* in_sizes, int n_in,
                              void* d_out, int out_size, void* d_ws, size_t ws_size,
                              hipStream_t stream) {
    (void)in_sizes; (void)n_in; (void)out_size; (void)ws_size;
    const float* x  = (const float*)d_in[0];
    const float* W0 = (const float*)d_in[1];
    const float* b0 = (const float*)d_in[2];
    const float* s0 = (const float*)d_in[3];
    const float* t0 = (const float*)d_in[4];
    const float* W1 = (const float*)d_in[5];
    const float* b1 = (const float*)d_in[6];
    const float* s1 = (const float*)d_in[7];
    const float* t1 = (const float*)d_in[8];
    const float* W2 = (const float*)d_in[9];
    const float* b2 = (const float*)d_in[10];
    const float* s2 = (const float*)d_in[11];
    const float* t2 = (const float*)d_in[12];
    const float* W3 = (const float*)d_in[13];
    const float* b3 = (const float*)d_in[14];
    const float* s3 = (const float*)d_in[15];
    const float* t3 = (const float*)d_in[16];
    const float* W4 = (const float*)d_in[17];
    const float* b4 = (const float*)d_in[18];
    const float* s4 = (const float*)d_in[19];
    const float* t4 = (const float*)d_in[20];
    const float* W5 = (const float*)d_in[21];
    const float* b5 = (const float*)d_in[22];

    uint32_t* gmax = (uint32_t*)d_ws;     // [8][128] u32

    hipMemsetAsync(gmax, 0, NB * 128 * sizeof(uint32_t), stream);  // enc(-inf) floor

    k1_fused<<<dim3(512), dim3(512), 0, stream>>>(
        x, W0, b0, s0, t0,
        W1, b1, s1, t1,
        W2, b2, s2, t2,
        W3, b3, s3, t3, gmax);
    k3_head<<<dim3(64), dim3(256), 0, stream>>>(gmax, W4, b4, s4, t4, W5, b5,
                                                (float*)d_out);
}

// Round 19
// 125.420 us; speedup vs baseline: 1.3164x; 1.0032x over previous
//
#include <hip/hip_runtime.h>
#include <hip/hip_bf16.h>
#include <cstdint>

#define NPTS 4096
#define NB 8
#define KNN 20
#define CAP 40

// LDS union layout (bytes): [0,64K) pts  ->  reused as A[64][132] + h1[64][68]
#define CVAL_OFF 65536
#define CIDX_OFF (CVAL_OFF + 8 * 4 * CAP * 4)
#define SEL_OFF  (CIDX_OFF + 8 * 4 * CAP * 4)
#define SMEM_SZ  (SEL_OFF + 8 * 4 * KNN * 4)     // 78336 B
#define H1_OFF   33792                            // 64*132*4

__device__ __forceinline__ float lrelu(float x) { return x >= 0.0f ? x : 0.2f * x; }

__device__ __forceinline__ uint32_t enc_f32(float f) {
    uint32_t u = __float_as_uint(f);
    return (u & 0x80000000u) ? ~u : (u | 0x80000000u);
}
__device__ __forceinline__ float dec_f32(uint32_t u) {
    return (u & 0x80000000u) ? __uint_as_float(u ^ 0x80000000u) : __uint_as_float(~u);
}

// XOR bank swizzle (verified R8: conflicts 110K -> 0 in both access patterns)
__device__ __forceinline__ int physidx(int i) {
    return (i & ~63) | ((i ^ (i >> 6)) & 63);
}

// ---------------------------------------------------------------------------
// K1: fused kNN + EdgeConv + max-k + pconv chain + max-pts (R18 structure).
//     R19 change: q read from the staged pts LDS (q = 0.5 * pts[r] -- exact
//     binary scaling, so the u computation is bit-identical) instead of 24
//     redundant wave-uniform global loads per thread.
// ---------------------------------------------------------------------------
__global__ __launch_bounds__(512, 4) void k1_fused(
        const float* __restrict__ x,
        const float* __restrict__ W0, const float* __restrict__ b0,
        const float* __restrict__ s0, const float* __restrict__ t0,
        const float* __restrict__ W1, const float* __restrict__ b1,
        const float* __restrict__ s1, const float* __restrict__ t1,
        const float* __restrict__ W2, const float* __restrict__ b2,
        const float* __restrict__ s2, const float* __restrict__ t2,
        const float* __restrict__ W3, const float* __restrict__ b3,
        const float* __restrict__ s3, const float* __restrict__ t3,
        uint32_t* __restrict__ gmax)
{
    __shared__ alignas(16) char smem[SMEM_SZ];
    __shared__ float sW0[64 * 6];
    __shared__ float sB[64], sS[64], sT[64];
    __shared__ uint32_t bmax[128];

    float4* pts = (float4*)smem;

    const int blk = blockIdx.x;
    const int b = blk >> 6;               // 64 blocks per batch
    const int rowbase = (blk & 63) << 6;  // 64 rows per block
    const int t = threadIdx.x;
    const int lane = t & 63;
    const int w = t >> 6;                 // wave 0..7

    const float* xb = x + (size_t)b * (NPTS * 3);

    // ---- single staging of all 4096 points ----
    for (int i = t; i < NPTS; i += 512) {
        float x0 = xb[3 * i], x1 = xb[3 * i + 1], x2 = xb[3 * i + 2];
        float pp = __fadd_rn(__fadd_rn(__fmul_rn(x0, x0), __fmul_rn(x1, x1)),
                             __fmul_rn(x2, x2));
        pts[physidx(i)] = make_float4(x0 + x0, x1 + x1, x2 + x2, -pp);
    }
    if (t < 64) {
        #pragma unroll
        for (int c = 0; c < 6; c++) sW0[t * 6 + c] = W0[t * 6 + c];
        sB[t] = b0[t]; sS[t] = s0[t]; sT[t] = t0[t];
    }
    if (t < 128) bmax[t] = 0u;

    const int r0 = rowbase + w * 8;
    __syncthreads();

    // q from LDS: pts holds (2x,2y,2z,-pp); 0.5x is EXACT -> bit-identical u.
    float qx[8], qy[8], qz[8];
    #pragma unroll
    for (int rr = 0; rr < 8; rr++) {
        float4 qp = pts[physidx(r0 + rr)];
        qx[rr] = 0.5f * qp.x;
        qy[rr] = 0.5f * qp.y;
        qz[rr] = 0.5f * qp.z;
    }

    // ---- P1: per-lane top-2 values + top-1 index, 8 rows ----
    float l0[8], l1v[8];
    int   l0i[8];
    #pragma unroll
    for (int rr = 0; rr < 8; rr++) {
        l0[rr] = -INFINITY; l1v[rr] = -INFINITY; l0i[rr] = 0x7FFFFFFF;
    }

    #pragma unroll 4
    for (int j = 0; j < 64; j++) {
        const float4 p = pts[(j << 6) | ((lane ^ j) & 63)];
        const int m = (j << 6) | lane;
        #pragma unroll
        for (int rr = 0; rr < 8; rr++) {
            float u = fmaf(qx[rr], p.x, fmaf(qy[rr], p.y, fmaf(qz[rr], p.z, p.w)));
            bool g0 = u > l0[rr];                                 // strict: first idx on ties
            l1v[rr] = __builtin_amdgcn_fmed3f(u, l0[rr], l1v[rr]);
            l0[rr] = fmaxf(u, l0[rr]);
            l0i[rr] = g0 ? m : l0i[rr];
        }
    }

    const float wa0 = sW0[lane * 6 + 0], wa1 = sW0[lane * 6 + 1], wa2 = sW0[lane * 6 + 2];
    const float wa0h = 0.5f * wa0, wa1h = 0.5f * wa1, wa2h = 0.5f * wa2;  // pts hold 2p
    const float wd0 = sW0[lane * 6 + 3] - wa0;
    const float wd1 = sW0[lane * 6 + 4] - wa1;
    const float wd2 = sW0[lane * 6 + 5] - wa2;

    float* cvalb = (float*)(smem + CVAL_OFF);
    int*   cidxb = (int*)(smem + CIDX_OFF);
    int*   selb  = (int*)(smem + SEL_OFF);

    float hz[8];   // h0 output, carried in registers across the LDS reuse

    for (int half = 0; half < 2; half++) {
        const int R = half * 4;

        // P2: 16-bit radix-ballot theta~
        uint32_t e0[4], e1[4], pr[4];
        #pragma unroll
        for (int rr = 0; rr < 4; rr++) {
            e0[rr] = enc_f32(l0[R + rr]);
            e1[rr] = enc_f32(l1v[R + rr]);
            pr[rr] = 0u;
        }
        for (int bit = 31; bit >= 16; bit--) {
            #pragma unroll
            for (int rr = 0; rr < 4; rr++) {
                uint32_t T = pr[rr] | (1u << bit);
                int c = __popcll(__ballot(e0[rr] >= T)) + __popcll(__ballot(e1[rr] >= T));
                if (c >= KNN) pr[rr] = T;
            }
        }
        float th[4];
        #pragma unroll
        for (int rr = 0; rr < 4; rr++) th[rr] = dec_f32(pr[rr]);

        // P3a: collect all u >= theta~.
        int nsel[4];
        #pragma unroll
        for (int rr = 0; rr < 4; rr++) {
            float* cval = cvalb + (w * 4 + rr) * CAP;
            int*   cidx = cidxb + (w * 4 + rr) * CAP;
            const float thv = th[rr];
            unsigned long long M1 = __ballot(l1v[R + rr] >= thv);
            bool single = (l0[R + rr] >= thv) && (l1v[R + rr] < thv);
            unsigned long long m0 = __ballot(single);
            if (single) {
                int pos = __popcll(m0 & ((1ull << lane) - 1ull));
                cval[pos] = l0[R + rr];
                cidx[pos] = l0i[R + rr];
            }
            int base = __popcll(m0);
            unsigned long long lm = M1;
            while (lm) {
                int L = __ffsll(lm) - 1; lm &= lm - 1;
                const float4 p = pts[(lane << 6) | ((L ^ lane) & 63)];
                float u = fmaf(qx[R + rr], p.x,
                          fmaf(qy[R + rr], p.y, fmaf(qz[R + rr], p.z, p.w)));
                unsigned long long hit = __ballot(u >= thv);
                if (u >= thv) {
                    int pos = base + __popcll(hit & ((1ull << lane) - 1ull));
                    if (pos < CAP) { cval[pos] = u; cidx[pos] = (lane << 6) | L; }
                }
                base += __popcll(hit);
            }
            nsel[rr] = min(base, CAP);
        }

        // P3b: exact top-20 by (value desc, idx asc) when n > 20
        #pragma unroll
        for (int rr = 0; rr < 4; rr++) {
            int n = nsel[rr];
            if (n > KNN) {
                float* cval = cvalb + (w * 4 + rr) * CAP;
                int*   cidx = cidxb + (w * 4 + rr) * CAP;
                int*   sel  = selb  + (w * 4 + rr) * KNN;
                bool act = lane < n;
                float ve = act ? cval[lane] : -INFINITY;
                int   ie = act ? cidx[lane] : 0x7FFFFFFF;
                int rk = 0;
                for (int f = 0; f < n; f++) {
                    float vf = cval[f];
                    int   if_ = cidx[f];
                    rk += ((vf > ve) || (vf == ve && if_ < ie)) ? 1 : 0;
                }
                if (act && rk < KNN) sel[rk] = ie;
            }
        }

        // P3c: consume -> hz (no global write)
        #pragma unroll
        for (int rr = 0; rr < 4; rr++) {
            int n = nsel[rr];
            bool ranked = n > KNN;
            int cnt20 = ranked ? KNN : n;
            const int* cidx = cidxb + (w * 4 + rr) * CAP;
            const int* sel  = selb  + (w * 4 + rr) * KNN;
            float mm = -INFINITY;
            for (int e = 0; e < cnt20; e++) {
                int g = ranked ? sel[e] : cidx[e];
                float4 p = pts[physidx(g)];
                float dotp = fmaf(wa2h, p.z, fmaf(wa1h, p.y, wa0h * p.x));
                mm = fmaxf(mm, dotp);
            }
            float cterm = fmaf(wd2, qz[R + rr], fmaf(wd1, qy[R + rr], wd0 * qx[R + rr]));
            float z = (mm + cterm + sB[lane]) * sS[lane] + sT[lane];
            hz[R + rr] = lrelu(z);
        }
    }

    // ================= MLP phase: reuse LDS =================
    __syncthreads();     // pts + collect arrays now dead
    float* A  = (float*)smem;            // [64][132]: h0 (64c) then h2 (128c)
    float* h1 = (float*)(smem + H1_OFF); // [64][68]

    {
        const int row = w * 8;
        #pragma unroll
        for (int rr = 0; rr < 8; rr++) A[(row + rr) * 132 + lane] = hz[rr];
    }
    __syncthreads();

    const int ps = t & 15;   // 16 point-slots, 4 pts each: {ps, ps+16, ps+32, ps+48}
    const int og = t >> 4;   // 0..31

    // ---- L1: 64 -> 64 ; outs o = og*2+[0,2) ----
    {
        float acc[4][2] = {};
        for (int c = 0; c < 64; c += 4) {
            float4 h[4];
            #pragma unroll
            for (int pp = 0; pp < 4; pp++)
                h[pp] = *(const float4*)&A[(ps + 16 * pp) * 132 + c];
            #pragma unroll
            for (int r = 0; r < 2; r++) {
                float4 wv = *(const float4*)&W1[(og * 2 + r) * 64 + c];
                #pragma unroll
                for (int pp = 0; pp < 4; pp++)
                    acc[pp][r] += h[pp].x * wv.x + h[pp].y * wv.y
                                + h[pp].z * wv.z + h[pp].w * wv.w;
            }
        }
        #pragma unroll
        for (int r = 0; r < 2; r++) {
            int o = og * 2 + r;
            float bb = b1[o], ss = s1[o], tt = t1[o];
            #pragma unroll
            for (int pp = 0; pp < 4; pp++)
                h1[(ps + 16 * pp) * 68 + o] = lrelu((acc[pp][r] + bb) * ss + tt);
        }
    }
    __syncthreads();

    // ---- L2: 64 -> 128 ; outs o = og*4+[0,4) ; h2 overwrites A ----
    {
        float acc[4][4] = {};
        for (int c = 0; c < 64; c += 4) {
            float4 h[4];
            #pragma unroll
            for (int pp = 0; pp < 4; pp++)
                h[pp] = *(const float4*)&h1[(ps + 16 * pp) * 68 + c];
            #pragma unroll
            for (int r = 0; r < 4; r++) {
                float4 wv = *(const float4*)&W2[(og * 4 + r) * 64 + c];
                #pragma unroll
                for (int pp = 0; pp < 4; pp++)
                    acc[pp][r] += h[pp].x * wv.x + h[pp].y * wv.y
                                + h[pp].z * wv.z + h[pp].w * wv.w;
            }
        }
        __syncthreads();   // all L1-era reads of A done before overwrite
        #pragma unroll
        for (int pp = 0; pp < 4; pp++) {
            float4 o4; float* po = (float*)&o4;
            #pragma unroll
            for (int r = 0; r < 4; r++) {
                int o = og * 4 + r;
                po[r] = lrelu((acc[pp][r] + b2[o]) * s2[o] + t2[o]);
            }
            *(float4*)&A[(ps + 16 * pp) * 132 + og * 4] = o4;
        }
    }
    __syncthreads();

    // ---- L3: 128 -> 128 + max over the block's 64 points ----
    {
        float acc[4][4] = {};
        for (int c = 0; c < 128; c += 4) {
            float4 h[4];
            #pragma unroll
            for (int pp = 0; pp < 4; pp++)
                h[pp] = *(const float4*)&A[(ps + 16 * pp) * 132 + c];
            #pragma unroll
            for (int r = 0; r < 4; r++) {
                float4 wv = *(const float4*)&W3[(og * 4 + r) * 128 + c];
                #pragma unroll
                for (int pp = 0; pp < 4; pp++)
                    acc[pp][r] += h[pp].x * wv.x + h[pp].y * wv.y
                                + h[pp].z * wv.z + h[pp].w * wv.w;
            }
        }
        float m[4];
        #pragma unroll
        for (int r = 0; r < 4; r++)
            m[r] = fmaxf(fmaxf(acc[0][r], acc[1][r]), fmaxf(acc[2][r], acc[3][r]));
        #pragma unroll
        for (int off = 1; off < 16; off <<= 1) {
            #pragma unroll
            for (int r = 0; r < 4; r++)
                m[r] = fmaxf(m[r], __shfl_xor(m[r], off));
        }
        if (ps == 0) {
            #pragma unroll
            for (int r = 0; r < 4; r++) {
                int o = og * 4 + r;
                float z = lrelu((m[r] + b3[o]) * s3[o] + t3[o]);
                atomicMax(&bmax[o], enc_f32(z));
            }
        }
    }
    __syncthreads();
    if (t < 128) atomicMax(&gmax[b * 128 + t], bmax[t]);
}

// ---------------------------------------------------------------------------
// K3: head 128 -> 512 (affine+lrelu) -> 1024.  64 blocks (8 batch x 8 chunk).
// ---------------------------------------------------------------------------
__global__ __launch_bounds__(256) void k3_head(
        const uint32_t* __restrict__ gmax,
        const float* __restrict__ W4, const float* __restrict__ b4,
        const float* __restrict__ s4, const float* __restrict__ t4,
        const float* __restrict__ W5, const float* __restrict__ b5,
        float* __restrict__ out)
{
    __shared__ float sIn[128];
    __shared__ float sH4[512];
    const int t = threadIdx.x;
    const int b = blockIdx.x >> 3;
    const int chunk = blockIdx.x & 7;

    if (t < 128) sIn[t] = dec_f32(gmax[b * 128 + t]);
    __syncthreads();

    #pragma unroll
    for (int rep = 0; rep < 2; rep++) {
        int o = t + rep * 256;
        const float4* wr = (const float4*)&W4[(size_t)o * 128];
        float acc = 0.f;
        for (int c4 = 0; c4 < 32; c4++) {
            float4 wv = wr[c4];
            acc += sIn[c4 * 4] * wv.x + sIn[c4 * 4 + 1] * wv.y
                 + sIn[c4 * 4 + 2] * wv.z + sIn[c4 * 4 + 3] * wv.w;
        }
        float z = (acc + b4[o]) * s4[o] + t4[o];
        sH4[o] = lrelu(z);
    }
    __syncthreads();

    if (t < 128) {
        int o = chunk * 128 + t;
        const float4* wr = (const float4*)&W5[(size_t)o * 512];
        float acc = 0.f;
        for (int c4 = 0; c4 < 128; c4++) {
            float4 wv = wr[c4];
            acc += sH4[c4 * 4] * wv.x + sH4[c4 * 4 + 1] * wv.y
                 + sH4[c4 * 4 + 2] * wv.z + sH4[c4 * 4 + 3] * wv.w;
        }
        out[(size_t)b * 1024 + o] = acc + b5[o];
    }
}

// ---------------------------------------------------------------------------
extern "C" void kernel_launch(void* const* d_in, const int* in_sizes, int n_in,
                              void* d_out, int out_size, void* d_ws, size_t ws_size,
                              hipStream_t stream) {
    (void)in_sizes; (void)n_in; (void)out_size; (void)ws_size;
    const float* x  = (const float*)d_in[0];
    const float* W0 = (const float*)d_in[1];
    const float* b0 = (const float*)d_in[2];
    const float* s0 = (const float*)d_in[3];
    const float* t0 = (const float*)d_in[4];
    const float* W1 = (const float*)d_in[5];
    const float* b1 = (const float*)d_in[6];
    const float* s1 = (const float*)d_in[7];
    const float* t1 = (const float*)d_in[8];
    const float* W2 = (const float*)d_in[9];
    const float* b2 = (const float*)d_in[10];
    const float* s2 = (const float*)d_in[11];
    const float* t2 = (const float*)d_in[12];
    const float* W3 = (const float*)d_in[13];
    const float* b3 = (const float*)d_in[14];
    const float* s3 = (const float*)d_in[15];
    const float* t3 = (const float*)d_in[16];
    const float* W4 = (const float*)d_in[17];
    const float* b4 = (const float*)d_in[18];
    const float* s4 = (const float*)d_in[19];
    const float* t4 = (const float*)d_in[20];
    const float* W5 = (const float*)d_in[21];
    const float* b5 = (const float*)d_in[22];

    uint32_t* gmax = (uint32_t*)d_ws;     // [8][128] u32

    hipMemsetAsync(gmax, 0, NB * 128 * sizeof(uint32_t), stream);  // enc(-inf) floor

    k1_fused<<<dim3(512), dim3(512), 0, stream>>>(
        x, W0, b0, s0, t0,
        W1, b1, s1, t1,
        W2, b2, s2, t2,
        W3, b3, s3, t3, gmax);
    k3_head<<<dim3(64), dim3(256), 0, stream>>>(gmax, W4, b4, s4, t4, W5, b5,
                                                (float*)d_out);
}